// Round 5
// baseline (369.993 us; speedup 1.0000x reference)
//
#include <hip/hip_runtime.h>

#define L 2048
#define H 8
#define S 128
#define B 8
#define HS 1024
#define NB 256   // persistent blocks == CU count: co-resident by construction

// Device-wide sense-reversing barrier (agent-scope atomics; all NB blocks resident).
__device__ __forceinline__ void grid_sync(unsigned* cnt, unsigned* gen) {
  __threadfence();            // make this thread's global writes visible device-wide
  __syncthreads();
  if (threadIdx.x == 0) {
    unsigned g = __hip_atomic_load(gen, __ATOMIC_ACQUIRE, __HIP_MEMORY_SCOPE_AGENT);
    unsigned old = __hip_atomic_fetch_add(cnt, 1u, __ATOMIC_ACQ_REL, __HIP_MEMORY_SCOPE_AGENT);
    if (old == NB - 1u) {
      __hip_atomic_store(cnt, 0u, __ATOMIC_RELAXED, __HIP_MEMORY_SCOPE_AGENT);
      __hip_atomic_fetch_add(gen, 1u, __ATOMIC_ACQ_REL, __HIP_MEMORY_SCOPE_AGENT);
    } else {
      while (__hip_atomic_load(gen, __ATOMIC_ACQUIRE, __HIP_MEMORY_SCOPE_AGENT) == g) {
        __builtin_amdgcn_s_sleep(2);
      }
    }
  }
  __syncthreads();
}

__global__ __launch_bounds__(256) void mega(const float* __restrict__ x,
                                            const float* __restrict__ W,
                                            const float* __restrict__ A,
                                            float* __restrict__ out,
                                            float* __restrict__ E,
                                            float* __restrict__ Z,
                                            float* __restrict__ partial_q,
                                            float* __restrict__ partial_v,
                                            float* __restrict__ u_pad,
                                            float* __restrict__ partial_s,
                                            float* __restrict__ scores,
                                            float* __restrict__ mxc,
                                            float* __restrict__ smc,
                                            float* __restrict__ partial,
                                            unsigned* __restrict__ bar) {
  const int wg = blockIdx.x;
  const int t = threadIdx.x;
  unsigned* cnt = bar;
  unsigned* gen = bar + 1;

  __shared__ union SM {
    float scan[256];
    struct { float ew[64][H]; float part[8][H][S]; } p1;   // 2KB + 16KB
    struct { float ql[128]; } p2;
    struct { float vs[HS]; float up[4][H][64]; } p3;       // 4KB + 8KB
    struct { float sred[H][128]; } p4;                     // 4KB
    struct { float red[256]; } p5;
    struct { float part[8][S]; } p6;                       // 4KB
  } sm;

  // ================= P0: E = exp(W) transposed, Z = causal prefix sums =================
  if (wg < H) {
    const int h = wg;
    const int d0 = t * 8;
    float e[8];
    float run = 0.f;
#pragma unroll
    for (int k = 0; k < 8; ++k) {
      float v = expf(W[(size_t)(d0 + k) * H + h]);
      e[k] = v; run += v;
    }
    sm.scan[t] = run;
    __syncthreads();
    for (int off = 1; off < 256; off <<= 1) {
      float v = (t >= off) ? sm.scan[t - off] : 0.f;
      __syncthreads();
      sm.scan[t] += v;
      __syncthreads();
    }
    float c = (t == 0) ? 0.f : sm.scan[t - 1];
#pragma unroll
    for (int k = 0; k < 8; ++k) {
      c += e[k];
      E[h * L + d0 + k] = e[k];
      Z[h * L + d0 + k] = c;
    }
  }
  grid_sync(cnt, gen);

  // ================= P1: partial_q[b,jc,h,s] = sum_{j in chunk jc} E[L-1-j,h]*x[b,j,s] =========
  {
    const int b = wg >> 5, jc = wg & 31;
    const int base = jc * 64;
#pragma unroll
    for (int k = 0; k < 2; ++k) {
      const int idx = t + k * 256;         // [0,512): i = idx>>3, h = idx&7
      const int i = idx >> 3, h = idx & 7;
      sm.p1.ew[i][h] = E[h * L + (L - 1 - base - i)];
    }
    __syncthreads();
    const int s4 = t & 31;
    const int r = t >> 5;
    const float4* __restrict__ x4 = (const float4*)(x + (size_t)b * L * S);
    float4 acc[H];
#pragma unroll
    for (int h = 0; h < H; ++h) acc[h] = make_float4(0.f, 0.f, 0.f, 0.f);
#pragma unroll
    for (int k = 0; k < 8; ++k) {
      const int ll = k * 8 + r;
      const int l = base + ll;
      const float4 xv = x4[(size_t)l * 32 + s4];
#pragma unroll
      for (int h = 0; h < H; ++h) {
        const float w = sm.p1.ew[ll][h];
        acc[h].x += w * xv.x; acc[h].y += w * xv.y;
        acc[h].z += w * xv.z; acc[h].w += w * xv.w;
      }
    }
#pragma unroll
    for (int h = 0; h < H; ++h) {
      sm.p1.part[r][h][s4 * 4 + 0] = acc[h].x;
      sm.p1.part[r][h][s4 * 4 + 1] = acc[h].y;
      sm.p1.part[r][h][s4 * 4 + 2] = acc[h].z;
      sm.p1.part[r][h][s4 * 4 + 3] = acc[h].w;
    }
    __syncthreads();
#pragma unroll
    for (int k = 0; k < 4; ++k) {
      const int idx = t + k * 256;         // h*S + s
      const int h = idx >> 7, s = idx & 127;
      float smv = 0.f;
#pragma unroll
      for (int rr = 0; rr < 8; ++rr) smv += sm.p1.part[rr][h][s];
      partial_q[((size_t)b * 32 + jc) * HS + idx] = smv;
    }
  }
  grid_sync(cnt, gen);

  // ================= P2: q-reduce + GEMV partial (d-chunks of 128, e-chunks of 256) ============
  {
    const int b = wg >> 5;
    const int r5 = wg & 31;
    const int ebase = (r5 & 3) * 256;
    const int dc = r5 >> 2;
    const int dbase = dc * 128;
    if (t < 128) {
      float acc = 0.f;
      const float* __restrict__ pq = partial_q + (size_t)b * 32 * HS + dbase + t;
#pragma unroll 8
      for (int jc = 0; jc < 32; ++jc) acc += pq[(size_t)jc * HS];
      const int h = (dbase + t) >> 7;
      sm.p2.ql[t] = acc / Z[h * L + (L - 1)];
    }
    __syncthreads();
    const int e = ebase + t;
    float a0 = 0.f, a1 = 0.f, a2 = 0.f, a3 = 0.f;
#pragma unroll 8
    for (int d = 0; d < 128; d += 4) {
      a0 += sm.p2.ql[d    ] * A[(size_t)(dbase + d    ) * HS + e];
      a1 += sm.p2.ql[d + 1] * A[(size_t)(dbase + d + 1) * HS + e];
      a2 += sm.p2.ql[d + 2] * A[(size_t)(dbase + d + 2) * HS + e];
      a3 += sm.p2.ql[d + 3] * A[(size_t)(dbase + d + 3) * HS + e];
    }
    partial_v[((size_t)b * 8 + dc) * HS + e] = (a0 + a1) + (a2 + a3);
  }
  grid_sync(cnt, gen);

  // ================= P3: v-reduce + u[b,h,j] = sum_s v[h*S+s]*x[b,j,s] ==========================
  {
    const int b = wg >> 5, jc = wg & 31;
#pragma unroll
    for (int k = 0; k < 4; ++k) {
      const int i = t + k * 256;
      float a = 0.f;
#pragma unroll
      for (int dc = 0; dc < 8; ++dc) a += partial_v[((size_t)b * 8 + dc) * HS + i];
      sm.p3.vs[i] = a;
    }
    __syncthreads();
    const int jl = t & 63, sq = t >> 6;
    const int j = jc * 64 + jl;
    const float4* __restrict__ xr = (const float4*)(x + ((size_t)b * L + j) * S) + sq * 8;
    float4 xv[8];
#pragma unroll
    for (int i = 0; i < 8; ++i) xv[i] = xr[i];
    float acc[H];
#pragma unroll
    for (int h = 0; h < H; ++h) {
      const float4* __restrict__ vv = (const float4*)(sm.p3.vs + h * S + sq * 32);
      float a = 0.f;
#pragma unroll
      for (int i = 0; i < 8; ++i) {
        const float4 w = vv[i];
        a += xv[i].x * w.x + xv[i].y * w.y + xv[i].z * w.z + xv[i].w * w.w;
      }
      acc[h] = a;
    }
#pragma unroll
    for (int h = 0; h < H; ++h) sm.p3.up[sq][h][jl] = acc[h];
    __syncthreads();
#pragma unroll
    for (int k = 0; k < 2; ++k) {
      const int idx = t + k * 256;       // h = idx>>6, j2 = idx&63
      const int h = idx >> 6, j2 = idx & 63;
      const float sv = sm.p3.up[0][h][j2] + sm.p3.up[1][h][j2] +
                       sm.p3.up[2][h][j2] + sm.p3.up[3][h][j2];
      const size_t rowbase = (size_t)(b * H + h) * (2 * L);
      u_pad[rowbase + jc * 64 + j2] = 0.f;
      u_pad[rowbase + L + jc * 64 + j2] = sv;
    }
  }
  grid_sync(cnt, gen);

  // ================= P4: conv tiles (1088 jobs strip-mined) =====================================
  for (int job = wg; job < B * 136; job += NB) {
    const int b = job / 136;
    int rr = job - b * 136;
    int lt = 0;
    while ((lt + 1) * (lt + 2) / 2 <= rr) ++lt;
    const int dt = rr - lt * (lt + 1) / 2;
    const int l0 = lt * 128;
    const int dbase = dt * 128;
    const int tsub = t & 31;
    const int h = t >> 5;
    const int Lb = l0 + tsub * 4;
    const float* __restrict__ ur = u_pad + (size_t)(b * H + h) * (2 * L) + L;
    const float4* __restrict__ Eh4 = (const float4*)(E + h * L);
    float acc0 = 0.f, acc1 = 0.f, acc2 = 0.f, acc3 = 0.f;
    float4 lo = *(const float4*)(ur + Lb - dbase - 4);
    float4 hi = *(const float4*)(ur + Lb - dbase);
#pragma unroll 4
    for (int dd = 0; dd < 128; dd += 4) {
      const int d0 = dbase + dd;
      float4 ev  = Eh4[d0 >> 2];
      float4 nlo = *(const float4*)(ur + Lb - d0 - 8);
      acc0 += ev.x * hi.x; acc1 += ev.x * hi.y; acc2 += ev.x * hi.z; acc3 += ev.x * hi.w;
      acc0 += ev.y * lo.w; acc1 += ev.y * hi.x; acc2 += ev.y * hi.y; acc3 += ev.y * hi.z;
      acc0 += ev.z * lo.z; acc1 += ev.z * lo.w; acc2 += ev.z * hi.x; acc3 += ev.z * hi.y;
      acc0 += ev.w * lo.y; acc1 += ev.w * lo.z; acc2 += ev.w * lo.w; acc3 += ev.w * hi.x;
      hi = lo; lo = nlo;
    }
    const float* __restrict__ Zh = Z + h * L;
    sm.p4.sred[h][tsub * 4 + 0] = acc0 / Zh[Lb + 0];
    sm.p4.sred[h][tsub * 4 + 1] = acc1 / Zh[Lb + 1];
    sm.p4.sred[h][tsub * 4 + 2] = acc2 / Zh[Lb + 2];
    sm.p4.sred[h][tsub * 4 + 3] = acc3 / Zh[Lb + 3];
    __syncthreads();
    if (t < 128) {
      float sc = 0.f;
#pragma unroll
      for (int hh = 0; hh < H; ++hh) sc += sm.p4.sred[hh][t];
      partial_s[((size_t)b * 16 + dt) * L + l0 + t] = sc;
    }
    __syncthreads();   // protect sred before next job overwrites
  }
  grid_sync(cnt, gen);

  // ================= P5: scores + per-chunk softmax stats (128 blocks x 128 l) =================
  if (wg < B * 16) {
    const int b = wg >> 4, lt = wg & 15;
    float scraw = -3.4e38f;
    if (t < 128) {
      const int l = lt * 128 + t;
      float s = 0.f;
      for (int dt = 0; dt <= lt; ++dt)
        s += partial_s[((size_t)b * 16 + dt) * L + l];
      scraw = (l == L - 1) ? -3.4e38f : s;
      scores[(size_t)b * L + l] = scraw;
    }
    sm.p5.red[t] = scraw;
    __syncthreads();
    for (int off = 128; off > 0; off >>= 1) {
      if (t < off) sm.p5.red[t] = fmaxf(sm.p5.red[t], sm.p5.red[t + off]);
      __syncthreads();
    }
    const float mx = sm.p5.red[0];
    __syncthreads();
    float e = (t < 128) ? expf(scraw - mx) : 0.f;   // scraw=-inf -> 0
    sm.p5.red[t] = e;
    __syncthreads();
    for (int off = 128; off > 0; off >>= 1) {
      if (t < off) sm.p5.red[t] += sm.p5.red[t + off];
      __syncthreads();
    }
    if (t == 0) { mxc[wg] = mx; smc[wg] = sm.p5.red[0]; }
  }
  grid_sync(cnt, gen);

  // ================= P6: weighted sums with on-the-fly p = exp(sc-mx)/den ======================
  {
    const int b = wg >> 5, c = wg & 31;
    float mx = -3.4e38f;
#pragma unroll
    for (int i = 0; i < 16; ++i) mx = fmaxf(mx, mxc[b * 16 + i]);
    float den = 0.f;
#pragma unroll
    for (int i = 0; i < 16; ++i) den += smc[b * 16 + i] * expf(mxc[b * 16 + i] - mx);
    const float inv = 1.f / den;
    const int s4 = t & 31, r = t >> 5;
    const int base = c * 64;
    const float4* __restrict__ x4 = (const float4*)(x + (size_t)b * L * S);
    float4 acc = make_float4(0.f, 0.f, 0.f, 0.f);
#pragma unroll
    for (int k = 0; k < 8; ++k) {
      const int l = base + r + k * 8;
      const float w = expf(scores[(size_t)b * L + l] - mx) * inv;
      const float4 xv = x4[(size_t)l * 32 + s4];
      acc.x += w * xv.x; acc.y += w * xv.y; acc.z += w * xv.z; acc.w += w * xv.w;
    }
    sm.p6.part[r][s4 * 4 + 0] = acc.x;
    sm.p6.part[r][s4 * 4 + 1] = acc.y;
    sm.p6.part[r][s4 * 4 + 2] = acc.z;
    sm.p6.part[r][s4 * 4 + 3] = acc.w;
    __syncthreads();
    if (t < S) {
      float sv = 0.f;
#pragma unroll
      for (int rr2 = 0; rr2 < 8; ++rr2) sv += sm.p6.part[rr2][t];
      partial[((size_t)b * 32 + c) * S + t] = sv;
    }
  }
  grid_sync(cnt, gen);

  // ================= P7: final reduce =================
  if (wg < B && t < S) {
    const int b = wg;
    float a = 0.f;
#pragma unroll 8
    for (int cc = 0; cc < 32; ++cc) a += partial[((size_t)b * 32 + cc) * S + t];
    out[b * S + t] = a;
  }
}

extern "C" void kernel_launch(void* const* d_in, const int* in_sizes, int n_in,
                              void* d_out, int out_size, void* d_ws, size_t ws_size,
                              hipStream_t stream) {
  const float* x = (const float*)d_in[0];   // (B, L, S) f32
  const float* W = (const float*)d_in[1];   // (L, H)   f32
  const float* A = (const float*)d_in[2];   // (HS, HS) f32
  float* out = (float*)d_out;               // (B, S)   f32

  unsigned* bar = (unsigned*)d_ws;                     // 2 words (cnt, gen)
  float* base      = (float*)d_ws + 16;                // keep 16B-aligned arrays
  float* E         = base;                             // H*L     = 16384
  float* Z         = E + H * L;                        // 16384
  float* partial_q = Z + H * L;                        // B*32*HS = 262144
  float* partial_v = partial_q + (size_t)B * 32 * HS;  // B*8*HS  = 65536
  float* u_pad     = partial_v + (size_t)B * 8 * HS;   // B*H*2L  = 262144
  float* partial_s = u_pad + (size_t)B * H * 2 * L;    // B*16*L  = 262144
  float* scores    = partial_s + (size_t)B * 16 * L;   // B*L     = 16384
  float* mxc       = scores + (size_t)B * L;           // B*16    = 128
  float* smc       = mxc + 128;                        // 128
  float* partial   = smc + 128;                        // B*32*S  = 32768
  // total ≈ 3.7 MB of d_ws

  hipMemsetAsync(bar, 0, 2 * sizeof(unsigned), stream);
  mega<<<NB, 256, 0, stream>>>(x, W, A, out, E, Z, partial_q, partial_v,
                               u_pad, partial_s, scores, mxc, smc, partial, bar);
}

// Round 6
// 235.992 us; speedup vs baseline: 1.5678x; 1.5678x over previous
//
#include <hip/hip_runtime.h>

#define L 2048
#define H 8
#define S 128
#define B 8
#define HS 1024
#define NB 256        // 1 block per CU: co-resident by construction (verified r5)
#define GBLK 32       // blocks per batch-group

// Contention-free per-group barrier: each block has a 64B-padded flag; it
// release-stores a monotonically increasing phase stamp, then wave-0 lanes
// poll the 32 flags of this block's group. No RMW, no reset (stamps increase).
__device__ __forceinline__ void group_sync(unsigned* flags, int wg, int phase) {
  __threadfence();                  // publish this block's global writes
  __syncthreads();
  const int t = threadIdx.x;
  const int g0 = (wg >> 5) << 5;    // first block of this group
  if (t == 0)
    __hip_atomic_store(flags + (size_t)wg * 16, (unsigned)phase,
                       __ATOMIC_RELEASE, __HIP_MEMORY_SCOPE_AGENT);
  if (t < GBLK) {
    unsigned* f = flags + (size_t)(g0 + t) * 16;
    while (__hip_atomic_load(f, __ATOMIC_ACQUIRE, __HIP_MEMORY_SCOPE_AGENT) <
           (unsigned)phase)
      __builtin_amdgcn_s_sleep(1);
  }
  __syncthreads();
}

__global__ __launch_bounds__(256) void mega(const float* __restrict__ x,
                                            const float* __restrict__ W,
                                            const float* __restrict__ A,
                                            float* __restrict__ out,
                                            float* __restrict__ Zb,
                                            float* __restrict__ partial_q,
                                            float* __restrict__ partial_v,
                                            float* __restrict__ u_pad,
                                            float* __restrict__ partial_s,
                                            float* __restrict__ scores,
                                            float* __restrict__ mxc,
                                            float* __restrict__ smc,
                                            float* __restrict__ partial,
                                            unsigned* __restrict__ flags) {
  const int wg = blockIdx.x;
  const int t = threadIdx.x;
  const int b = wg >> 5;
  const int jc = wg & 31;

  __shared__ float scan[256];
  __shared__ float ew[64][H];
  __shared__ float part[8][H][S];
  __shared__ float ql[128];
  __shared__ float vs[HS];
  __shared__ float up[4][H][64];
  __shared__ float echunk[H][128];
  __shared__ float sred[H][128];
  __shared__ float red[256];

  // ===== P1a: 8 blocks per group compute this group's private Z copy =====
  if (jc < H) {
    const int h = jc;
    const int d0 = t * 8;
    float e[8];
    float run = 0.f;
#pragma unroll
    for (int k = 0; k < 8; ++k) {
      float v = expf(W[(size_t)(d0 + k) * H + h]);
      e[k] = v; run += v;
    }
    scan[t] = run;
    __syncthreads();
    for (int off = 1; off < 256; off <<= 1) {
      float v = (t >= off) ? scan[t - off] : 0.f;
      __syncthreads();
      scan[t] += v;
      __syncthreads();
    }
    float c = (t == 0) ? 0.f : scan[t - 1];
#pragma unroll
    for (int k = 0; k < 8; ++k) {
      c += e[k];
      Zb[((size_t)(b * H + h)) * L + d0 + k] = c;
    }
  }

  // ===== P1b: partial_q[b,jc,h,s] = sum_{j in chunk jc} E[L-1-j,h]*x[b,j,s] =====
  {
    const int base = jc * 64;
    const int dhi = L - 1 - base;
#pragma unroll
    for (int k = 0; k < 2; ++k) {
      const int idx = t + k * 256;        // [0,512): i = idx>>3, h = idx&7
      const int i = idx >> 3, h = idx & 7;
      ew[i][h] = expf(W[(size_t)(dhi - i) * H + h]);
    }
    __syncthreads();
    const int s4 = t & 31;
    const int r = t >> 5;
    const float4* __restrict__ x4 = (const float4*)(x + (size_t)b * L * S);
    float4 acc[H];
#pragma unroll
    for (int h = 0; h < H; ++h) acc[h] = make_float4(0.f, 0.f, 0.f, 0.f);
#pragma unroll
    for (int k = 0; k < 8; ++k) {
      const int ll = k * 8 + r;
      const int l = base + ll;
      const float4 xv = x4[(size_t)l * 32 + s4];
#pragma unroll
      for (int h = 0; h < H; ++h) {
        const float w = ew[ll][h];
        acc[h].x += w * xv.x; acc[h].y += w * xv.y;
        acc[h].z += w * xv.z; acc[h].w += w * xv.w;
      }
    }
#pragma unroll
    for (int h = 0; h < H; ++h) {
      part[r][h][s4 * 4 + 0] = acc[h].x;
      part[r][h][s4 * 4 + 1] = acc[h].y;
      part[r][h][s4 * 4 + 2] = acc[h].z;
      part[r][h][s4 * 4 + 3] = acc[h].w;
    }
    __syncthreads();
#pragma unroll
    for (int k = 0; k < 4; ++k) {
      const int idx = t + k * 256;        // h*S + s
      const int h = idx >> 7, s = idx & 127;
      float smv = 0.f;
#pragma unroll
      for (int rr = 0; rr < 8; ++rr) smv += part[rr][h][s];
      partial_q[((size_t)b * 32 + jc) * HS + idx] = smv;
    }
  }
  group_sync(flags, wg, 1);

  // ===== P2: q-reduce + GEMV partial (4 e-chunks x 8 d-chunks of 128) =====
  {
    const int ebase = (jc & 3) * 256;
    const int dc = jc >> 2;
    const int dbase = dc * 128;
    if (t < 128) {
      float acc = 0.f;
      const float* __restrict__ pq = partial_q + (size_t)b * 32 * HS + dbase + t;
#pragma unroll 8
      for (int j2 = 0; j2 < 32; ++j2) acc += pq[(size_t)j2 * HS];
      const int h = (dbase + t) >> 7;
      ql[t] = acc / Zb[((size_t)(b * H + h)) * L + (L - 1)];
    }
    __syncthreads();
    const int e = ebase + t;
    float a0 = 0.f, a1 = 0.f, a2 = 0.f, a3 = 0.f;
#pragma unroll 8
    for (int d = 0; d < 128; d += 4) {
      a0 += ql[d    ] * A[(size_t)(dbase + d    ) * HS + e];
      a1 += ql[d + 1] * A[(size_t)(dbase + d + 1) * HS + e];
      a2 += ql[d + 2] * A[(size_t)(dbase + d + 2) * HS + e];
      a3 += ql[d + 3] * A[(size_t)(dbase + d + 3) * HS + e];
    }
    partial_v[((size_t)b * 8 + dc) * HS + e] = (a0 + a1) + (a2 + a3);
  }
  group_sync(flags, wg, 2);

  // ===== P3: v-reduce + u[b,h,j] = sum_s v[h*S+s]*x[b,j,s] =====
  {
#pragma unroll
    for (int k = 0; k < 4; ++k) {
      const int i = t + k * 256;
      float a = 0.f;
#pragma unroll
      for (int dc = 0; dc < 8; ++dc) a += partial_v[((size_t)b * 8 + dc) * HS + i];
      vs[i] = a;
    }
    __syncthreads();
    const int jl = t & 63, sq = t >> 6;
    const int j = jc * 64 + jl;
    const float4* __restrict__ xr = (const float4*)(x + ((size_t)b * L + j) * S) + sq * 8;
    float4 xv[8];
#pragma unroll
    for (int i = 0; i < 8; ++i) xv[i] = xr[i];
    float acc[H];
#pragma unroll
    for (int h = 0; h < H; ++h) {
      const float4* __restrict__ vv = (const float4*)(vs + h * S + sq * 32);
      float a = 0.f;
#pragma unroll
      for (int i = 0; i < 8; ++i) {
        const float4 w = vv[i];
        a += xv[i].x * w.x + xv[i].y * w.y + xv[i].z * w.z + xv[i].w * w.w;
      }
      acc[h] = a;
    }
#pragma unroll
    for (int h = 0; h < H; ++h) up[sq][h][jl] = acc[h];
    __syncthreads();
#pragma unroll
    for (int k = 0; k < 2; ++k) {
      const int idx = t + k * 256;       // h = idx>>6, j2 = idx&63
      const int h = idx >> 6, j2 = idx & 63;
      const float sv = up[0][h][j2] + up[1][h][j2] + up[2][h][j2] + up[3][h][j2];
      const size_t rowbase = (size_t)(b * H + h) * (2 * L);
      u_pad[rowbase + jc * 64 + j2] = 0.f;
      u_pad[rowbase + L + jc * 64 + j2] = sv;
    }
  }
  group_sync(flags, wg, 3);

  // ===== P4: conv tiles — 136 triangular jobs per batch over its 32 blocks =====
  for (int job = jc; job < 136; job += GBLK) {
    int lt = 0;
    while ((lt + 1) * (lt + 2) / 2 <= job) ++lt;
    const int dt = job - lt * (lt + 1) / 2;
    const int l0 = lt * 128;
    const int dbase = dt * 128;
    const int tsub = t & 31;
    const int h = t >> 5;
    // local E chunk for this tile (recomputed; removes cross-group E dependency)
#pragma unroll
    for (int k = 0; k < 4; ++k) {
      const int i = tsub * 4 + k;
      echunk[h][i] = expf(W[(size_t)(dbase + i) * H + h]);
    }
    __syncthreads();
    const int Lb = l0 + tsub * 4;
    const float* __restrict__ ur = u_pad + (size_t)(b * H + h) * (2 * L) + L;
    float acc0 = 0.f, acc1 = 0.f, acc2 = 0.f, acc3 = 0.f;
    float4 lo = *(const float4*)(ur + Lb - dbase - 4);
    float4 hi = *(const float4*)(ur + Lb - dbase);
#pragma unroll 4
    for (int dd = 0; dd < 128; dd += 4) {
      const float4 ev = *(const float4*)(&echunk[h][dd]);   // wave-uniform LDS
      const float4 nlo = *(const float4*)(ur + Lb - (dbase + dd) - 8);
      acc0 += ev.x * hi.x; acc1 += ev.x * hi.y; acc2 += ev.x * hi.z; acc3 += ev.x * hi.w;
      acc0 += ev.y * lo.w; acc1 += ev.y * hi.x; acc2 += ev.y * hi.y; acc3 += ev.y * hi.z;
      acc0 += ev.z * lo.z; acc1 += ev.z * lo.w; acc2 += ev.z * hi.x; acc3 += ev.z * hi.y;
      acc0 += ev.w * lo.y; acc1 += ev.w * lo.z; acc2 += ev.w * lo.w; acc3 += ev.w * hi.x;
      hi = lo; lo = nlo;
    }
    const float* __restrict__ Zh = Zb + (size_t)(b * H + h) * L;
    sred[h][tsub * 4 + 0] = acc0 / Zh[Lb + 0];
    sred[h][tsub * 4 + 1] = acc1 / Zh[Lb + 1];
    sred[h][tsub * 4 + 2] = acc2 / Zh[Lb + 2];
    sred[h][tsub * 4 + 3] = acc3 / Zh[Lb + 3];
    __syncthreads();
    if (t < 128) {
      float sc = 0.f;
#pragma unroll
      for (int hh = 0; hh < H; ++hh) sc += sred[hh][t];
      partial_s[((size_t)b * 16 + dt) * L + l0 + t] = sc;
    }
    __syncthreads();   // protect sred/echunk before next job
  }
  group_sync(flags, wg, 4);

  // ===== P5: scores + per-chunk softmax stats (16 of 32 blocks) =====
  if (jc < 16) {
    const int lt = jc;
    float scraw = -3.4e38f;
    if (t < 128) {
      const int l = lt * 128 + t;
      float s = 0.f;
      for (int dt = 0; dt <= lt; ++dt)
        s += partial_s[((size_t)b * 16 + dt) * L + l];
      scraw = (l == L - 1) ? -3.4e38f : s;
      scores[(size_t)b * L + l] = scraw;
    }
    red[t] = scraw;
    __syncthreads();
    for (int off = 128; off > 0; off >>= 1) {
      if (t < off) red[t] = fmaxf(red[t], red[t + off]);
      __syncthreads();
    }
    const float mx = red[0];
    __syncthreads();
    float e = (t < 128) ? expf(scraw - mx) : 0.f;   // scraw=-inf -> 0
    red[t] = e;
    __syncthreads();
    for (int off = 128; off > 0; off >>= 1) {
      if (t < off) red[t] += red[t + off];
      __syncthreads();
    }
    if (t == 0) { mxc[b * 16 + lt] = mx; smc[b * 16 + lt] = red[0]; }
  }
  group_sync(flags, wg, 5);

  // ===== P6: weighted sums with on-the-fly p = exp(sc-mx)/den =====
  {
    float mx = -3.4e38f;
#pragma unroll
    for (int i = 0; i < 16; ++i) mx = fmaxf(mx, mxc[b * 16 + i]);
    float den = 0.f;
#pragma unroll
    for (int i = 0; i < 16; ++i) den += smc[b * 16 + i] * expf(mxc[b * 16 + i] - mx);
    const float inv = 1.f / den;
    const int s4 = t & 31, r = t >> 5;
    const int base = jc * 64;
    const float4* __restrict__ x4 = (const float4*)(x + (size_t)b * L * S);
    float4 acc = make_float4(0.f, 0.f, 0.f, 0.f);
#pragma unroll
    for (int k = 0; k < 8; ++k) {
      const int l = base + r + k * 8;
      const float w = expf(scores[(size_t)b * L + l] - mx) * inv;
      const float4 xv = x4[(size_t)l * 32 + s4];
      acc.x += w * xv.x; acc.y += w * xv.y; acc.z += w * xv.z; acc.w += w * xv.w;
    }
    part[0][r][s4 * 4 + 0] = acc.x;      // reuse P1 LDS
    part[0][r][s4 * 4 + 1] = acc.y;
    part[0][r][s4 * 4 + 2] = acc.z;
    part[0][r][s4 * 4 + 3] = acc.w;
    __syncthreads();
    if (t < S) {
      float sv = 0.f;
#pragma unroll
      for (int rr2 = 0; rr2 < 8; ++rr2) sv += part[0][rr2][t];
      partial[((size_t)b * 32 + jc) * S + t] = sv;
    }
  }
  group_sync(flags, wg, 6);

  // ===== P7: final reduce (1 block per batch) =====
  if (jc == 0 && t < S) {
    float a = 0.f;
#pragma unroll 8
    for (int cc = 0; cc < 32; ++cc) a += partial[((size_t)b * 32 + cc) * S + t];
    out[b * S + t] = a;
  }
}

extern "C" void kernel_launch(void* const* d_in, const int* in_sizes, int n_in,
                              void* d_out, int out_size, void* d_ws, size_t ws_size,
                              hipStream_t stream) {
  const float* x = (const float*)d_in[0];   // (B, L, S) f32
  const float* W = (const float*)d_in[1];   // (L, H)   f32
  const float* A = (const float*)d_in[2];   // (HS, HS) f32
  float* out = (float*)d_out;               // (B, S)   f32

  unsigned* flags = (unsigned*)d_ws;                   // NB*16 uints = 16KB (64B/flag)
  float* fbase     = (float*)d_ws + NB * 16;
  float* Zb        = fbase;                            // B*H*L   = 131072
  float* partial_q = Zb + (size_t)B * H * L;           // B*32*HS = 262144
  float* partial_v = partial_q + (size_t)B * 32 * HS;  // B*8*HS  = 65536
  float* u_pad     = partial_v + (size_t)B * 8 * HS;   // B*H*2L  = 262144
  float* partial_s = u_pad + (size_t)B * H * 2 * L;    // B*16*L  = 262144
  float* scores    = partial_s + (size_t)B * 16 * L;   // B*L     = 16384
  float* mxc       = scores + (size_t)B * L;           // 128
  float* smc       = mxc + 128;                        // 128
  float* partial   = smc + 128;                        // B*32*S  = 32768
  // total ≈ 4.1 MB of d_ws

  hipMemsetAsync(flags, 0, NB * 16 * sizeof(unsigned), stream);
  mega<<<NB, 256, 0, stream>>>(x, W, A, out, Zb, partial_q, partial_v,
                               u_pad, partial_s, scores, mxc, smc, partial, flags);
}

// Round 7
// 68.319 us; speedup vs baseline: 5.4157x; 3.4543x over previous
//
#include <hip/hip_runtime.h>

#define L 2048
#define H 8
#define S 128
#define B 8
#define HS 1024

// ============ KA: fused {E,Z prefix-scan} + partial_q ============
// grid (B, 32). Every block recomputes its own 64x8 exp(W) slice in LDS.
// Blocks (b==0, jc<8) additionally do the full prefix scan for h=jc -> E,Z.
// partial_q[b,jc,h,s] = sum_{j in chunk jc} E[L-1-j,h] * x[b,j,s]
__global__ __launch_bounds__(256) void kA_prep_qpart(const float* __restrict__ W,
                                                     const float* __restrict__ x,
                                                     float* __restrict__ E,
                                                     float* __restrict__ Z,
                                                     float* __restrict__ partial_q,
                                                     unsigned* __restrict__ counter) {
  const int b = blockIdx.x, jc = blockIdx.y;
  const int t = threadIdx.x;
  if (b == 0 && jc == 0 && t == 0) *counter = 0u;   // reset for kF's last-block gate

  __shared__ float ew[64][H];       // ew[i][h] = E[h, L-1-(base+i)]
  __shared__ float part[8][H][S];   // [r][h][s]
  __shared__ float tot[256];        // scan scratch

  const int base = jc * 64;
  const int dhi = L - 1 - base;
#pragma unroll
  for (int k = 0; k < 2; ++k) {
    const int idx = t + k * 256;    // [0,512): i = idx>>3, h = idx&7
    const int i = idx >> 3, h = idx & 7;
    ew[i][h] = expf(W[(size_t)(dhi - i) * H + h]);
  }

  // --- full prefix scan for one h (8 blocks only) ---
  if (b == 0 && jc < H) {
    const int h = jc;
    const int d0 = t * 8;
    float e[8];
    float run = 0.f;
#pragma unroll
    for (int k = 0; k < 8; ++k) {
      float v = expf(W[(size_t)(d0 + k) * H + h]);
      e[k] = v; run += v;
    }
    tot[t] = run;
    __syncthreads();
    for (int off = 1; off < 256; off <<= 1) {
      float v = (t >= off) ? tot[t - off] : 0.f;
      __syncthreads();
      tot[t] += v;
      __syncthreads();
    }
    float c = (t == 0) ? 0.f : tot[t - 1];
#pragma unroll
    for (int k = 0; k < 8; ++k) {
      c += e[k];
      E[h * L + d0 + k] = e[k];
      Z[h * L + d0 + k] = c;
    }
  }
  __syncthreads();   // ew ready (and scan done)

  // --- partial_q main loop ---
  const int s4 = t & 31;
  const int r = t >> 5;
  const float4* __restrict__ x4 = (const float4*)(x + (size_t)b * L * S);
  float4 acc[H];
#pragma unroll
  for (int h = 0; h < H; ++h) acc[h] = make_float4(0.f, 0.f, 0.f, 0.f);
#pragma unroll
  for (int k = 0; k < 8; ++k) {
    const int ll = k * 8 + r;
    const int l = base + ll;
    const float4 xv = x4[(size_t)l * 32 + s4];
#pragma unroll
    for (int h = 0; h < H; ++h) {
      const float w = ew[ll][h];
      acc[h].x += w * xv.x; acc[h].y += w * xv.y;
      acc[h].z += w * xv.z; acc[h].w += w * xv.w;
    }
  }
#pragma unroll
  for (int h = 0; h < H; ++h) {
    part[r][h][s4 * 4 + 0] = acc[h].x;
    part[r][h][s4 * 4 + 1] = acc[h].y;
    part[r][h][s4 * 4 + 2] = acc[h].z;
    part[r][h][s4 * 4 + 3] = acc[h].w;
  }
  __syncthreads();
#pragma unroll
  for (int k = 0; k < 4; ++k) {
    const int idx = t + k * 256;           // h*S + s
    const int h = idx >> 7, s = idx & 127;
    float sm = 0.f;
#pragma unroll
    for (int rr = 0; rr < 8; ++rr) sm += part[rr][h][s];
    partial_q[((size_t)b * 32 + jc) * HS + idx] = sm;
  }
}

// ============ KB: all-batch GEMV over one A-chunk ============
// grid (4 ec, 16 dc) = 64 blocks. ebase = ec*256 (256 e), dbase = dc*64 (64 d).
// Phase 1: ql[b][dl] = (sum_jc partial_q[b,jc,dbase+dl]) * invZ (h uniform per block).
// Phase 2: partial_v[b,dc,e] = sum_d ql[b][d] * A[dbase+d, e]. A traffic = 4 MB total.
__global__ __launch_bounds__(256) void kB_v(const float* __restrict__ partial_q,
                                            const float* __restrict__ Z,
                                            const float* __restrict__ A,
                                            float* __restrict__ partial_v) {
  const int ebase = blockIdx.x * 256;
  const int dc = blockIdx.y;
  const int dbase = dc * 64;
  const int t = threadIdx.x;
  __shared__ float ql[8][64];
  const float invZ = 1.f / Z[(dc >> 1) * L + (L - 1)];   // h = dbase>>7 = dc>>1
#pragma unroll
  for (int k = 0; k < 2; ++k) {
    const int o = t + k * 256;          // [0,512): b = o>>6, dl = o&63
    const int bb = o >> 6, dl = o & 63;
    const float* __restrict__ pq = partial_q + ((size_t)bb * 32) * HS + dbase + dl;
    float a0 = 0.f, a1 = 0.f, a2 = 0.f, a3 = 0.f;
#pragma unroll 2
    for (int j4 = 0; j4 < 32; j4 += 4) {
      a0 += pq[(size_t)(j4 + 0) * HS];
      a1 += pq[(size_t)(j4 + 1) * HS];
      a2 += pq[(size_t)(j4 + 2) * HS];
      a3 += pq[(size_t)(j4 + 3) * HS];
    }
    ql[bb][dl] = ((a0 + a1) + (a2 + a3)) * invZ;
  }
  __syncthreads();
  const int e = ebase + t;
  const float* __restrict__ Ab = A + (size_t)dbase * HS + e;
  float acc[8] = {0.f, 0.f, 0.f, 0.f, 0.f, 0.f, 0.f, 0.f};
  for (int d4 = 0; d4 < 16; ++d4) {
    float4 qv[8];
#pragma unroll
    for (int bb = 0; bb < 8; ++bb) qv[bb] = *(const float4*)&ql[bb][d4 * 4];
#pragma unroll
    for (int dd = 0; dd < 4; ++dd) {
      const float a = Ab[(size_t)(d4 * 4 + dd) * HS];
      acc[0] += ((const float*)&qv[0])[dd] * a;
      acc[1] += ((const float*)&qv[1])[dd] * a;
      acc[2] += ((const float*)&qv[2])[dd] * a;
      acc[3] += ((const float*)&qv[3])[dd] * a;
      acc[4] += ((const float*)&qv[4])[dd] * a;
      acc[5] += ((const float*)&qv[5])[dd] * a;
      acc[6] += ((const float*)&qv[6])[dd] * a;
      acc[7] += ((const float*)&qv[7])[dd] * a;
    }
  }
#pragma unroll
  for (int bb = 0; bb < 8; ++bb)
    partial_v[((size_t)bb * 16 + dc) * HS + e] = acc[bb];
}

// ============ KC: fused v-reduce + u ============
// grid (B, 32), 256 threads: jl = t&63, sq = t>>6 (4-way s split)
__global__ __launch_bounds__(256) void kC_u(const float* __restrict__ x,
                                            const float* __restrict__ partial_v,
                                            float* __restrict__ u_pad) {
  const int b = blockIdx.x, jc = blockIdx.y;
  const int t = threadIdx.x;
  __shared__ float vs[HS];
  __shared__ float up[4][H][64];
#pragma unroll
  for (int k = 0; k < 4; ++k) {
    const int i = t + k * 256;
    float a = 0.f;
#pragma unroll
    for (int dcc = 0; dcc < 16; ++dcc) a += partial_v[((size_t)b * 16 + dcc) * HS + i];
    vs[i] = a;
  }
  __syncthreads();
  const int jl = t & 63, sq = t >> 6;
  const int j = jc * 64 + jl;
  const float4* __restrict__ xr = (const float4*)(x + ((size_t)b * L + j) * S) + sq * 8;
  float4 xv[8];
#pragma unroll
  for (int i = 0; i < 8; ++i) xv[i] = xr[i];
  float acc[H];
#pragma unroll
  for (int h = 0; h < H; ++h) {
    const float4* __restrict__ vv = (const float4*)(vs + h * S + sq * 32);
    float a = 0.f;
#pragma unroll
    for (int i = 0; i < 8; ++i) {
      const float4 w = vv[i];   // same addr across wave -> LDS broadcast
      a += xv[i].x * w.x + xv[i].y * w.y + xv[i].z * w.z + xv[i].w * w.w;
    }
    acc[h] = a;
  }
#pragma unroll
  for (int h = 0; h < H; ++h) up[sq][h][jl] = acc[h];
  __syncthreads();
#pragma unroll
  for (int k = 0; k < 2; ++k) {
    const int idx = t + k * 256;       // [0,512): h = idx>>6, j2 = idx&63
    const int h = idx >> 6, j2 = idx & 63;
    const float s = up[0][h][j2] + up[1][h][j2] + up[2][h][j2] + up[3][h][j2];
    const size_t rowbase = (size_t)(b * H + h) * (2 * L);
    u_pad[rowbase + jc * 64 + j2] = 0.f;        // zero pad (front half)
    u_pad[rowbase + L + jc * 64 + j2] = s;
  }
}

// ============ KD: conv partials, flat triangular grid of B*136 blocks ============
__global__ __launch_bounds__(256) void kD_conv(const float* __restrict__ u_pad,
                                               const float* __restrict__ E,
                                               const float* __restrict__ Z,
                                               float* __restrict__ partial_s) {
  const int job = blockIdx.x;
  const int b = job / 136;
  const int rr = job - b * 136;
  int lt = 0;
  while ((lt + 1) * (lt + 2) / 2 <= rr) ++lt;
  const int dt = rr - lt * (lt + 1) / 2;
  const int l0 = lt * 128;
  const int dbase = dt * 128;
  const int t = threadIdx.x;
  const int tsub = t & 31;
  const int h = t >> 5;
  const int Lb = l0 + tsub * 4;
  const float* __restrict__ ur = u_pad + (size_t)(b * H + h) * (2 * L) + L;
  const float4* __restrict__ Eh4 = (const float4*)(E + h * L);
  float acc0 = 0.f, acc1 = 0.f, acc2 = 0.f, acc3 = 0.f;
  float4 lo = *(const float4*)(ur + Lb - dbase - 4);
  float4 hi = *(const float4*)(ur + Lb - dbase);
#pragma unroll 4
  for (int dd = 0; dd < 128; dd += 4) {
    const int d0 = dbase + dd;
    float4 ev  = Eh4[d0 >> 2];
    float4 nlo = *(const float4*)(ur + Lb - d0 - 8);
    acc0 += ev.x * hi.x; acc1 += ev.x * hi.y; acc2 += ev.x * hi.z; acc3 += ev.x * hi.w;
    acc0 += ev.y * lo.w; acc1 += ev.y * hi.x; acc2 += ev.y * hi.y; acc3 += ev.y * hi.z;
    acc0 += ev.z * lo.z; acc1 += ev.z * lo.w; acc2 += ev.z * hi.x; acc3 += ev.z * hi.y;
    acc0 += ev.w * lo.y; acc1 += ev.w * lo.z; acc2 += ev.w * lo.w; acc3 += ev.w * hi.x;
    hi = lo; lo = nlo;
  }
  __shared__ float sred[H][128];
  const float* __restrict__ Zh = Z + h * L;
  sred[h][tsub * 4 + 0] = acc0 / Zh[Lb + 0];
  sred[h][tsub * 4 + 1] = acc1 / Zh[Lb + 1];
  sred[h][tsub * 4 + 2] = acc2 / Zh[Lb + 2];
  sred[h][tsub * 4 + 3] = acc3 / Zh[Lb + 3];
  __syncthreads();
  if (t < 128) {
    float sc = 0.f;
#pragma unroll
    for (int hh = 0; hh < H; ++hh) sc += sred[hh][t];
    partial_s[((size_t)b * 16 + dt) * L + l0 + t] = sc;
  }
}

// ============ KE: score reduce + softmax -> normalized p ============
// grid (B); thread t owns l in [8t, 8t+8)
__global__ __launch_bounds__(256) void kE_soft(const float* __restrict__ partial_s,
                                               float* __restrict__ p) {
  const int b = blockIdx.x;
  const int t = threadIdx.x;
  __shared__ float red[256];
  const int l0 = t * 8;
  const int lt = t >> 4;                 // (8t)>>7
  float sc[8];
#pragma unroll
  for (int k = 0; k < 8; ++k) sc[k] = 0.f;
  for (int dt = 0; dt <= lt; ++dt) {
    const float4* __restrict__ ps = (const float4*)(partial_s + ((size_t)b * 16 + dt) * L + l0);
    const float4 a = ps[0], c = ps[1];
    sc[0] += a.x; sc[1] += a.y; sc[2] += a.z; sc[3] += a.w;
    sc[4] += c.x; sc[5] += c.y; sc[6] += c.z; sc[7] += c.w;
  }
  if (t == 255) sc[7] = -3.4e38f;        // l = 2047 excluded
  float mx = sc[0];
#pragma unroll
  for (int k = 1; k < 8; ++k) mx = fmaxf(mx, sc[k]);
  red[t] = mx;
  __syncthreads();
  for (int off = 128; off > 0; off >>= 1) {
    if (t < off) red[t] = fmaxf(red[t], red[t + off]);
    __syncthreads();
  }
  mx = red[0];
  __syncthreads();
  float e[8];
  float sm = 0.f;
#pragma unroll
  for (int k = 0; k < 8; ++k) {
    e[k] = (l0 + k < L - 1) ? expf(sc[k] - mx) : 0.f;
    sm += e[k];
  }
  red[t] = sm;
  __syncthreads();
  for (int off = 128; off > 0; off >>= 1) {
    if (t < off) red[t] += red[t + off];
    __syncthreads();
  }
  const float inv = 1.f / red[0];
  float4* __restrict__ pp = (float4*)(p + (size_t)b * L + l0);
  pp[0] = make_float4(e[0] * inv, e[1] * inv, e[2] * inv, e[3] * inv);
  pp[1] = make_float4(e[4] * inv, e[5] * inv, e[6] * inv, e[7] * inv);
}

// ============ KF: weighted sum partials + last-block final reduce ============
__global__ __launch_bounds__(256) void kF_out(const float* __restrict__ x,
                                              const float* __restrict__ p,
                                              float* __restrict__ partial,
                                              unsigned* __restrict__ counter,
                                              float* __restrict__ out) {
  const int b = blockIdx.x, c = blockIdx.y;
  const int t = threadIdx.x;
  const int s4 = t & 31;
  const int r = t >> 5;
  const int base = c * 64;
  const float4* __restrict__ x4 = (const float4*)(x + (size_t)b * L * S);
  const float* __restrict__ pb = p + (size_t)b * L;
  float4 acc = make_float4(0.f, 0.f, 0.f, 0.f);
#pragma unroll
  for (int k = 0; k < 8; ++k) {
    const int l = base + r + k * 8;
    const float w = pb[l];
    const float4 xv = x4[(size_t)l * 32 + s4];
    acc.x += w * xv.x; acc.y += w * xv.y; acc.z += w * xv.z; acc.w += w * xv.w;
  }
  __shared__ float part[8][S];
  part[r][s4 * 4 + 0] = acc.x;
  part[r][s4 * 4 + 1] = acc.y;
  part[r][s4 * 4 + 2] = acc.z;
  part[r][s4 * 4 + 3] = acc.w;
  __syncthreads();
  if (t < S) {
    float sm = 0.f;
#pragma unroll
    for (int rr = 0; rr < 8; ++rr) sm += part[rr][t];
    partial[((size_t)b * 32 + c) * S + t] = sm;
  }
  // --- last-block gate (one-shot, no spinning) ---
  __threadfence();
  __syncthreads();
  __shared__ unsigned lastFlag;
  if (t == 0) {
    const unsigned old = atomicAdd(counter, 1u);
    lastFlag = (old == (unsigned)(B * 32 - 1)) ? 1u : 0u;
  }
  __syncthreads();
  if (lastFlag) {
#pragma unroll
    for (int k = 0; k < 4; ++k) {
      const int idx = t + k * 256;   // b2 = idx>>7, s = idx&127
      const int b2 = idx >> 7, s = idx & 127;
      float a = 0.f;
      for (int cc = 0; cc < 32; ++cc) a += partial[((size_t)b2 * 32 + cc) * S + s];
      out[b2 * S + s] = a;
    }
  }
}

extern "C" void kernel_launch(void* const* d_in, const int* in_sizes, int n_in,
                              void* d_out, int out_size, void* d_ws, size_t ws_size,
                              hipStream_t stream) {
  const float* x = (const float*)d_in[0];   // (B, L, S) f32
  const float* W = (const float*)d_in[1];   // (L, H)   f32
  const float* A = (const float*)d_in[2];   // (HS, HS) f32
  float* out = (float*)d_out;               // (B, S)   f32

  float* ws        = (float*)d_ws;
  float* E         = ws;                               // H*L     = 16384
  float* Z         = E + H * L;                        // 16384
  float* partial_q = Z + H * L;                        // B*32*HS = 262144
  float* partial_v = partial_q + (size_t)B * 32 * HS;  // B*16*HS = 131072
  float* u_pad     = partial_v + (size_t)B * 16 * HS;  // B*H*2L  = 262144
  float* partial_s = u_pad + (size_t)B * H * 2 * L;    // B*16*L  = 262144
  float* p         = partial_s + (size_t)B * 16 * L;   // B*L     = 16384
  float* partial   = p + B * L;                        // B*32*S  = 32768
  unsigned* counter = (unsigned*)(partial + (size_t)B * 32 * S);
  // total ≈ 4 MB of d_ws

  kA_prep_qpart<<<dim3(B, 32),   256, 0, stream>>>(W, x, E, Z, partial_q, counter);
  kB_v         <<<dim3(4, 16),   256, 0, stream>>>(partial_q, Z, A, partial_v);
  kC_u         <<<dim3(B, 32),   256, 0, stream>>>(x, partial_v, u_pad);
  kD_conv      <<<B * 136,       256, 0, stream>>>(u_pad, E, Z, partial_s);
  kE_soft      <<<B, 256, 0, stream>>>(partial_s, p);
  kF_out       <<<dim3(B, 32),   256, 0, stream>>>(x, p, partial, counter, out);
}